// Round 1
// baseline (426.628 us; speedup 1.0000x reference)
//
#include <hip/hip_runtime.h>

// SpikingAuditory: B=1M envs, 6 Izhikevich neurons x 10 steps, 3-channel column.
// One thread per environment. Memory-bound on the noise tensor (251.7 MB).
// fp contract OFF inside the kernel to bit-match the numpy reference's
// separate mul/add rounding (spike threshold v>=30 is bit-sensitive).

#define STEPS 10
#define NNEUR 6

__global__ __launch_bounds__(256) void spiking_auditory_kernel(
    const float* __restrict__ pd_in, const float* __restrict__ cc_in,
    const float* __restrict__ an_in, const float* __restrict__ so_in,
    const float* __restrict__ pl_in, const float* __restrict__ pm_in,
    const float* __restrict__ ph_in,
    const float* __restrict__ v0_in, const float* __restrict__ u0_in,
    const float* __restrict__ r0_in, const float* __restrict__ noise_in,
    float* __restrict__ out, int B)
{
#pragma clang fp contract(off)
    int b = blockIdx.x * blockDim.x + threadIdx.x;
    if (b >= B) return;

    float pd = pd_in[b], cc = cc_in[b], an = an_in[b], so = so_in[b];
    float pl = pl_in[b], pm = pm_in[b], ph = ph_in[b];

    // --- frequency-band drives (match numpy op grouping; no fma in these) ---
    float low = 0.0f;
    if (pd < 200.0f) {
        float t = (200.0f - pd) / 200.0f;
        t = fmaxf(0.0f, t);
        low = t * t;
    }
    float mid = 0.0f;
    if (cc < 150.0f) {
        float t = (150.0f - cc) / 150.0f;
        t = fmaxf(0.0f, t);
        mid = t * 0.8f;
    }
    float high = fminf(1.0f, (an * 0.3f) + so);

    float d_low  = fabsf(low - pl);
    float d_mid  = fabsf(mid - pm);
    float d_high = fabsf(high - ph);
    float salience = ((d_low * 0.4f) + (d_mid * 0.3f)) + (d_high * 0.3f);

    bool startle = (so > 0.6f) || ((d_low > 0.4f) && (low > 0.5f));

    // --- input currents for the 6 neurons ---
    float I[NNEUR];
    I[0] = low * 12.0f;  I[1] = low * 8.0f;
    I[2] = mid * 12.0f;  I[3] = mid * 8.0f;
    I[4] = high * 12.0f; I[5] = high * 8.0f;

    // --- load initial neuron state (stride-24B across lanes; neighbors fill lines) ---
    size_t base6 = (size_t)b * NNEUR;
    float v[NNEUR], u[NNEUR], rate[NNEUR];
    {
        float2 a = *(const float2*)(v0_in + base6);
        float2 c = *(const float2*)(v0_in + base6 + 2);
        float2 e = *(const float2*)(v0_in + base6 + 4);
        v[0]=a.x; v[1]=a.y; v[2]=c.x; v[3]=c.y; v[4]=e.x; v[5]=e.y;
    }
    {
        float2 a = *(const float2*)(u0_in + base6);
        float2 c = *(const float2*)(u0_in + base6 + 2);
        float2 e = *(const float2*)(u0_in + base6 + 4);
        u[0]=a.x; u[1]=a.y; u[2]=c.x; u[3]=c.y; u[4]=e.x; u[5]=e.y;
    }
    {
        float2 a = *(const float2*)(r0_in + base6);
        float2 c = *(const float2*)(r0_in + base6 + 2);
        float2 e = *(const float2*)(r0_in + base6 + 4);
        rate[0]=a.x; rate[1]=a.y; rate[2]=c.x; rate[3]=c.y; rate[4]=e.x; rate[5]=e.y;
    }

    // --- 10-step Izhikevich scan ---
    size_t step_stride = (size_t)B * NNEUR;
    const float* nz_base = noise_in + base6;
    #pragma unroll
    for (int s = 0; s < STEPS; ++s) {
        const float* nzp = nz_base + (size_t)s * step_stride;
        float2 n0 = *(const float2*)(nzp);
        float2 n1 = *(const float2*)(nzp + 2);
        float2 n2 = *(const float2*)(nzp + 4);
        float nz[NNEUR] = {n0.x, n0.y, n1.x, n1.y, n2.x, n2.y};
        #pragma unroll
        for (int n = 0; n < NNEUR; ++n) {
            // Iin = (I + nz*0.3) + (-1.0)
            float Iin = (I[n] + (nz[n] * 0.3f)) + (-1.0f);
            float vv = v[n];
            // v += ((0.04*v)*v + 5.0*v) + 140 - u + Iin   (DT=1, numpy grouping)
            float t = ((0.04f * vv) * vv) + (5.0f * vv);
            t = t + 140.0f;
            t = t - u[n];
            t = t + Iin;
            vv = vv + t;
            // u += 0.02*((0.2*v_new) - u)
            float uu = u[n] + (0.02f * ((0.2f * vv) - u[n]));
            bool spike = (vv >= 30.0f);
            v[n] = spike ? -65.0f : vv;
            u[n] = spike ? (uu + 8.0f) : uu;
            rate[n] = (0.9f * rate[n]) + (0.1f * (spike ? 1.0f : 0.0f));
        }
    }

    // --- two-compartment column: 4 neurons/channel are identical -> 1 scalar/ch ---
    float sens[3] = {low, mid, high};
    float fe = 0.0f, pe_abs_sum = 0.0f, prec_sum = 0.0f;
    #pragma unroll
    for (int ch = 0; ch < 3; ++ch) {
        float sv = sens[ch];
        float vd = 0.0f, vs = 0.0f;
        #pragma unroll
        for (int t = 0; t < 8; ++t) {
            vd = vd + (0.125f * ((-vd) + sv));                       // prediction == sensory
            vs = vs + (0.125f * (((-vs) + sv) + (0.5f * vd)));
        }
        float pe  = vs - vd;
        float pe2 = pe * pe;
        float pr  = 1.0f / (1.0f + pe2);
        fe = fe + ((0.5f * pr) * pe2 + 0.5f * log1pf(pe2));
        pe_abs_sum = pe_abs_sum + fabsf(pe);
        prec_sum   = prec_sum + pr;
    }
    float pe_mean   = pe_abs_sum / 3.0f;
    float prec_mean = prec_sum / 3.0f;

    float rsum = ((((rate[0] + rate[1]) + rate[2]) + rate[3]) + rate[4]) + rate[5];
    float rate_mean = rsum / 6.0f;

    // --- store: out[B,8] then startle[B] as 0/1 float ---
    float4 o0 = make_float4(low, mid, high, salience);
    float4 o1 = make_float4(pe_mean, prec_mean, fe, rate_mean);
    *(float4*)(out + (size_t)b * 8)     = o0;
    *(float4*)(out + (size_t)b * 8 + 4) = o1;
    out[(size_t)B * 8 + b] = startle ? 1.0f : 0.0f;
}

extern "C" void kernel_launch(void* const* d_in, const int* in_sizes, int n_in,
                              void* d_out, int out_size, void* d_ws, size_t ws_size,
                              hipStream_t stream) {
    const float* pd = (const float*)d_in[0];
    const float* cc = (const float*)d_in[1];
    const float* an = (const float*)d_in[2];
    const float* so = (const float*)d_in[3];
    const float* pl = (const float*)d_in[4];
    const float* pm = (const float*)d_in[5];
    const float* ph = (const float*)d_in[6];
    const float* v0 = (const float*)d_in[7];
    const float* u0 = (const float*)d_in[8];
    const float* r0 = (const float*)d_in[9];
    const float* nz = (const float*)d_in[10];
    float* out = (float*)d_out;
    int B = in_sizes[0];

    int block = 256;
    int grid = (B + block - 1) / block;
    spiking_auditory_kernel<<<grid, block, 0, stream>>>(
        pd, cc, an, so, pl, pm, ph, v0, u0, r0, nz, out, B);
}